// Round 3
// baseline (1716.740 us; speedup 1.0000x reference)
//
#include <hip/hip_runtime.h>
#include <hip/hip_bf16.h>

// ---------------- problem constants ----------------
#define T_TOK 4096
#define HD    2048
#define NE    64
#define TOPK  8
#define IMID  512
#define N13   1024                 // 2*I
#define NPAIR (T_TOK*TOPK)         // 32768
#define NROWS (NPAIR + T_TOK)      // 36864
#define MAXT2 208                  // >= sum ceil(cnt_e/256) worst case
#define RSCALE 2.5f

typedef __attribute__((ext_vector_type(8))) __bf16 bf16x8;
typedef __attribute__((ext_vector_type(4))) __bf16 bf16x4;
typedef __attribute__((ext_vector_type(4))) float  f32x4;

// ---------------- init: zero out + counters ----------------
__global__ __launch_bounds__(256) void init_kernel(float4* __restrict__ out4,
                                                   int* __restrict__ counts,
                                                   int* __restrict__ curs) {
  int gid = blockIdx.x * 256 + threadIdx.x;
  float4 z; z.x = z.y = z.z = z.w = 0.f;
  out4[gid] = z;                       // grid == T_TOK*HD/4/256 exactly
  if (gid < NE + 1) { counts[gid] = 0; curs[gid] = 0; }
}

// ---------------- hidden fp32 -> bf16 prepass ----------------
__global__ __launch_bounds__(256) void cvt_kernel(const float4* __restrict__ hs4,
                                                  bf16x8* __restrict__ hb8) {
  int gid = blockIdx.x * 256 + threadIdx.x;    // T_TOK*HD/8 threads
  float4 a = hs4[2 * gid], b = hs4[2 * gid + 1];
  bf16x8 v = { (__bf16)a.x, (__bf16)a.y, (__bf16)a.z, (__bf16)a.w,
               (__bf16)b.x, (__bf16)b.y, (__bf16)b.z, (__bf16)b.w };
  hb8[gid] = v;
}

// ---------------- router logits: 64 tokens/block, full K, no atomics ----------------
__global__ __launch_bounds__(256) void logits_kernel(const float* __restrict__ hs,
                                                     const float* __restrict__ gw,
                                                     float* __restrict__ logits) {
  __shared__ float hsm[64][64];
  __shared__ float gwm[64][64];
  int tid = threadIdx.x;
  int tb = blockIdx.x * 64;
  int tok = tid & 63, kq = tid >> 6;
  int tq = (tid & 15) * 4, eq = (tid >> 4) * 4;
  float acc[4][4] = {};
  for (int c = 0; c < 32; ++c) {
    int kb = c * 64;
#pragma unroll
    for (int it = 0; it < 4; ++it) {
      int k4 = kq * 16 + it * 4;
      float4 f = *(const float4*)&hs[(size_t)(tb + tok) * HD + kb + k4];
      hsm[k4 + 0][tok] = f.x; hsm[k4 + 1][tok] = f.y;
      hsm[k4 + 2][tok] = f.z; hsm[k4 + 3][tok] = f.w;
      int q = tid + it * 256;
      int grow = q >> 4, gc = (q & 15) * 4;
      *(float4*)&gwm[grow][gc] = *(const float4*)&gw[(size_t)(kb + grow) * NE + gc];
    }
    __syncthreads();
#pragma unroll 8
    for (int k = 0; k < 64; ++k) {
      float4 g = *(const float4*)&gwm[k][eq];
      float h0 = hsm[k][tq + 0], h1 = hsm[k][tq + 1];
      float h2 = hsm[k][tq + 2], h3 = hsm[k][tq + 3];
      acc[0][0] += h0 * g.x; acc[0][1] += h0 * g.y; acc[0][2] += h0 * g.z; acc[0][3] += h0 * g.w;
      acc[1][0] += h1 * g.x; acc[1][1] += h1 * g.y; acc[1][2] += h1 * g.z; acc[1][3] += h1 * g.w;
      acc[2][0] += h2 * g.x; acc[2][1] += h2 * g.y; acc[2][2] += h2 * g.z; acc[2][3] += h2 * g.w;
      acc[3][0] += h3 * g.x; acc[3][1] += h3 * g.y; acc[3][2] += h3 * g.z; acc[3][3] += h3 * g.w;
    }
    __syncthreads();
  }
#pragma unroll
  for (int i = 0; i < 4; ++i)
#pragma unroll
    for (int j = 0; j < 4; ++j)
      logits[(size_t)(tb + tq + i) * NE + eq + j] = acc[i][j];
}

// ---------------- sigmoid + top-8 ----------------
__global__ __launch_bounds__(256) void top8_kernel(const float* __restrict__ logits,
                                                   int* __restrict__ topk_id,
                                                   float* __restrict__ pair_w,
                                                   int* __restrict__ counts) {
  int lane = threadIdx.x & 63;
  int t = blockIdx.x * 4 + (threadIdx.x >> 6);
  float v = logits[(size_t)t * NE + lane];
  float s = 1.f / (1.f + __expf(-v));
  float cur = s, ssum = 0.f;
  int myid = 0; float myw = 0.f;
  for (int k = 0; k < TOPK; ++k) {
    float bv = cur; int bi = lane;
#pragma unroll
    for (int off = 32; off >= 1; off >>= 1) {
      float ov = __shfl_xor(bv, off);
      int   oi = __shfl_xor(bi, off);
      if (ov > bv || (ov == bv && oi < bi)) { bv = ov; bi = oi; }
    }
    ssum += bv;
    if (lane == k) { myid = bi; myw = bv; }
    if (lane == bi) cur = -1.f;
  }
  if (lane < TOPK) {
    topk_id[(size_t)t * TOPK + lane] = myid;
    pair_w[(size_t)t * TOPK + lane] = myw / ssum * RSCALE;
    atomicAdd(&counts[myid], 1);
  }
}

// ---------------- scan: offsets + 256-row tile table ----------------
__global__ void scan_kernel(int* __restrict__ counts, int* __restrict__ offs,
                            int2* __restrict__ tiles) {
  if (threadIdx.x != 0) return;
  counts[NE] = T_TOK;
  int off = 0, tix = 0;
  for (int e = 0; e <= NE; ++e) {
    offs[e] = off;
    int c = counts[e];
    int nt = (c + 255) >> 8;
    for (int i = 0; i < nt; ++i) {
      int rr = c - i * 256; if (rr > 256) rr = 256;
      tiles[tix++] = make_int2(off + i * 256, (e << 16) | rr);
    }
    off += c;
  }
  for (; tix < MAXT2; ++tix) tiles[tix] = make_int2(0, 0);
}

// ---------------- scatter ----------------
__global__ __launch_bounds__(256) void scatter_kernel(const int* __restrict__ topk_id,
                                                      const float* __restrict__ pair_w,
                                                      const int* __restrict__ offs,
                                                      int* __restrict__ curs,
                                                      int* __restrict__ row_token,
                                                      float* __restrict__ row_w) {
  int p = blockIdx.x * 256 + threadIdx.x;
  int dst, t; float w;
  if (p < NPAIR) {
    t = p >> 3; int e = topk_id[p]; w = pair_w[p];
    dst = offs[e] + atomicAdd(&curs[e], 1);
  } else {
    t = p - NPAIR; w = 1.0f;
    dst = offs[NE] + t;                      // deterministic, no atomic
  }
  row_token[dst] = t;
  row_w[dst] = w;
}

// ---------------- helpers ----------------
__device__ __forceinline__ int swz(int row, int kbyte) {     // [row][64 bf16 = 128B]
  return row * 128 + (kbyte ^ ((row & 7) << 4));
}
__device__ __forceinline__ void barrier_lgkm() {
  asm volatile("s_waitcnt lgkmcnt(0)" ::: "memory");
  __builtin_amdgcn_s_barrier();
  __builtin_amdgcn_sched_barrier(0);
}
// transpose 4 k-rows x 2 cols fp32 -> two bf16x4 column slivers
__device__ __forceinline__ void store_b4(__bf16* Bs, int c2, int kbyte, const float2* p) {
  bf16x4 c0 = { (__bf16)p[0].x, (__bf16)p[1].x, (__bf16)p[2].x, (__bf16)p[3].x };
  bf16x4 c1 = { (__bf16)p[0].y, (__bf16)p[1].y, (__bf16)p[2].y, (__bf16)p[3].y };
  *(bf16x4*)&Bs[swz(c2,     kbyte) >> 1] = c0;
  *(bf16x4*)&Bs[swz(c2 + 1, kbyte) >> 1] = c1;
}
// transpose 8 k-rows x 2 cols fp32 -> two bf16x8 column slivers
__device__ __forceinline__ void store_b8(__bf16* Bs, int c2, int kbyte, const float2* p) {
  bf16x8 c0 = { (__bf16)p[0].x, (__bf16)p[1].x, (__bf16)p[2].x, (__bf16)p[3].x,
                (__bf16)p[4].x, (__bf16)p[5].x, (__bf16)p[6].x, (__bf16)p[7].x };
  bf16x8 c1 = { (__bf16)p[0].y, (__bf16)p[1].y, (__bf16)p[2].y, (__bf16)p[3].y,
                (__bf16)p[4].y, (__bf16)p[5].y, (__bf16)p[6].y, (__bf16)p[7].y };
  *(bf16x8*)&Bs[swz(c2,     kbyte) >> 1] = c0;
  *(bf16x8*)&Bs[swz(c2 + 1, kbyte) >> 1] = c1;
}

// ---------------- grouped GEMM1: BM=256, BN=64g+64u, BK=64, A-single + B-dbuf -----------
// grid (8 nb, MAXT2 tile): linear id = nb + 8*tile -> same-expert adjacent tiles share XCD.
__global__ __launch_bounds__(512, 4) void gemm1_kernel(const __bf16* __restrict__ hidden_bf,
                                                       const float* __restrict__ w13,
                                                       const float* __restrict__ sw13,
                                                       const int* __restrict__ row_token,
                                                       const int2* __restrict__ tiles,
                                                       __bf16* __restrict__ hbuf) {
  int2 td = tiles[blockIdx.y];
  int rows = td.y & 0xFFFF;
  if (rows == 0) return;
  int e = td.y >> 16, row0 = td.x;
  const float* W = (e < NE) ? (w13 + (size_t)e * (HD * N13)) : sw13;  // [2048][1024]
  int n0 = blockIdx.x * 64;                                           // gate cols; up at +512

  __shared__ __bf16 As[256 * 64];      // 32 KB single-buffered
  __shared__ __bf16 Bgs[2][64 * 64];   // 16 KB
  __shared__ __bf16 Bus[2][64 * 64];   // 16 KB  -> total 64 KB

  int tid = threadIdx.x;
  int lane = tid & 63, wv = tid >> 6;
  int l15 = lane & 15, lq = lane >> 4;

  int arow = tid >> 1, ahalf = tid & 1;
  int grow = row0 + arow; if (grow >= NROWS) grow = NROWS - 1;
  const __bf16* Ap = hidden_bf + (size_t)row_token[grow] * HD + ahalf * 32;

  int c2 = (tid & 31) * 2, kq = tid >> 5;        // kq in [0,16): 4 k-rows each
  const float* Bg0 = W + (size_t)(kq * 4) * N13 + n0 + c2;
  const float* Bu0 = Bg0 + 512;

  bf16x8 pa[4]; float2 pg[4], pu[4];
#pragma unroll
  for (int i = 0; i < 4; ++i) pa[i] = *(const bf16x8*)(Ap + i * 8);
#pragma unroll
  for (int r = 0; r < 4; ++r) {
    pg[r] = *(const float2*)(Bg0 + (size_t)r * N13);
    pu[r] = *(const float2*)(Bu0 + (size_t)r * N13);
  }
#pragma unroll
  for (int i = 0; i < 4; ++i) *(bf16x8*)&As[swz(arow, ahalf * 64 + i * 16) >> 1] = pa[i];
  store_b4(Bgs[0], c2, kq * 8, pg);
  store_b4(Bus[0], c2, kq * 8, pu);

  f32x4 accg[2][4], accu[2][4];
#pragma unroll
  for (int i = 0; i < 2; ++i)
#pragma unroll
    for (int j = 0; j < 4; ++j) { accg[i][j] = (f32x4)(0.f); accu[i][j] = (f32x4)(0.f); }

  for (int s = 0; s < 32; ++s) {
    int cur = s & 1;
    if (s + 1 < 32) {                  // prefetch next K-step into regs
      const __bf16* Ap2 = Ap + (s + 1) * 64;
      const float* Bg2 = Bg0 + (size_t)(s + 1) * 64 * N13;
      const float* Bu2 = Bu0 + (size_t)(s + 1) * 64 * N13;
#pragma unroll
      for (int i = 0; i < 4; ++i) pa[i] = *(const bf16x8*)(Ap2 + i * 8);
#pragma unroll
      for (int r = 0; r < 4; ++r) {
        pg[r] = *(const float2*)(Bg2 + (size_t)r * N13);
        pu[r] = *(const float2*)(Bu2 + (size_t)r * N13);
      }
    }
    barrier_lgkm();                    // staging writes of step s visible
#pragma unroll
    for (int kk = 0; kk < 2; ++kk) {
      int koff = kk * 64 + lq * 16;
      bf16x8 a[2], bg[4], bu[4];
#pragma unroll
      for (int i = 0; i < 2; ++i)
        a[i] = *(const bf16x8*)&As[swz(wv * 32 + i * 16 + l15, koff) >> 1];
#pragma unroll
      for (int j = 0; j < 4; ++j) {
        bg[j] = *(const bf16x8*)&Bgs[cur][swz(j * 16 + l15, koff) >> 1];
        bu[j] = *(const bf16x8*)&Bus[cur][swz(j * 16 + l15, koff) >> 1];
      }
#pragma unroll
      for (int i = 0; i < 2; ++i)
#pragma unroll
        for (int j = 0; j < 4; ++j) {
          accg[i][j] = __builtin_amdgcn_mfma_f32_16x16x32_bf16(a[i], bg[j], accg[i][j], 0, 0, 0);
          accu[i][j] = __builtin_amdgcn_mfma_f32_16x16x32_bf16(a[i], bu[j], accu[i][j], 0, 0, 0);
        }
    }
    barrier_lgkm();                    // all As reads done before overwrite
    if (s + 1 < 32) {
#pragma unroll
      for (int i = 0; i < 4; ++i) *(bf16x8*)&As[swz(arow, ahalf * 64 + i * 16) >> 1] = pa[i];
      store_b4(Bgs[cur ^ 1], c2, kq * 8, pg);
      store_b4(Bus[cur ^ 1], c2, kq * 8, pu);
    }
  }
  // epilogue: h = silu(g)*u
#pragma unroll
  for (int mi = 0; mi < 2; ++mi) {
#pragma unroll
    for (int r = 0; r < 4; ++r) {
      int rl = wv * 32 + mi * 16 + lq * 4 + r;
      if (rl < rows) {
        size_t hrow = (size_t)(row0 + rl) * IMID;
#pragma unroll
        for (int j = 0; j < 4; ++j) {
          float g = accg[mi][j][r], u = accu[mi][j][r];
          float hv = g * u / (1.f + __expf(-g));
          hbuf[hrow + n0 + j * 16 + l15] = (__bf16)hv;
        }
      }
    }
  }
}

// ---------------- grouped GEMM2: BM=256, BN=128, BK=64, A-single + B-dbuf, atomic out ---
__global__ __launch_bounds__(512, 4) void gemm2_kernel(const __bf16* __restrict__ hbuf,
                                                       const float* __restrict__ w2,
                                                       const float* __restrict__ sw2,
                                                       const int* __restrict__ row_token,
                                                       const float* __restrict__ row_w,
                                                       const int2* __restrict__ tiles,
                                                       float* __restrict__ out) {
  int2 td = tiles[blockIdx.y];
  int rows = td.y & 0xFFFF;
  if (rows == 0) return;
  int e = td.y >> 16, row0 = td.x;
  const float* W = (e < NE) ? (w2 + (size_t)e * (IMID * HD)) : sw2;   // [512][2048]
  int n0 = blockIdx.x * 128;

  __shared__ __bf16 As[256 * 64];      // 32 KB single
  __shared__ __bf16 Bs[2][128 * 64];   // 32 KB dbuf -> 64 KB

  int tid = threadIdx.x;
  int lane = tid & 63, wv = tid >> 6, wr = wv >> 1, wc = wv & 1;
  int l15 = lane & 15, lq = lane >> 4;

  int arow = tid >> 1, ahalf = tid & 1;
  int agrow = row0 + arow; if (agrow >= NROWS) agrow = NROWS - 1;
  const __bf16* Ap = hbuf + (size_t)agrow * IMID + ahalf * 32;

  int c2 = (tid & 63) * 2, kq = tid >> 6;        // kq in [0,8): 8 k-rows each
  const float* Bp0 = W + (size_t)(kq * 8) * HD + n0 + c2;

  bf16x8 pa[4]; float2 pb[8];
#pragma unroll
  for (int i = 0; i < 4; ++i) pa[i] = *(const bf16x8*)(Ap + i * 8);
#pragma unroll
  for (int r = 0; r < 8; ++r) pb[r] = *(const float2*)(Bp0 + (size_t)r * HD);
#pragma unroll
  for (int i = 0; i < 4; ++i) *(bf16x8*)&As[swz(arow, ahalf * 64 + i * 16) >> 1] = pa[i];
  store_b8(Bs[0], c2, kq * 16, pb);

  f32x4 acc[4][4];
#pragma unroll
  for (int i = 0; i < 4; ++i)
#pragma unroll
    for (int j = 0; j < 4; ++j) acc[i][j] = (f32x4)(0.f);

  for (int s = 0; s < 8; ++s) {
    int cur = s & 1;
    if (s + 1 < 8) {
      const __bf16* Ap2 = Ap + (s + 1) * 64;
      const float* Bp2 = Bp0 + (size_t)(s + 1) * 64 * HD;
#pragma unroll
      for (int i = 0; i < 4; ++i) pa[i] = *(const bf16x8*)(Ap2 + i * 8);
#pragma unroll
      for (int r = 0; r < 8; ++r) pb[r] = *(const float2*)(Bp2 + (size_t)r * HD);
    }
    barrier_lgkm();
#pragma unroll
    for (int kk = 0; kk < 2; ++kk) {
      int koff = kk * 64 + lq * 16;
      bf16x8 a[4], b[4];
#pragma unroll
      for (int i = 0; i < 4; ++i)
        a[i] = *(const bf16x8*)&As[swz(wr * 64 + i * 16 + l15, koff) >> 1];
#pragma unroll
      for (int j = 0; j < 4; ++j)
        b[j] = *(const bf16x8*)&Bs[cur][swz(wc * 64 + j * 16 + l15, koff) >> 1];
#pragma unroll
      for (int i = 0; i < 4; ++i)
#pragma unroll
        for (int j = 0; j < 4; ++j)
          acc[i][j] = __builtin_amdgcn_mfma_f32_16x16x32_bf16(a[i], b[j], acc[i][j], 0, 0, 0);
    }
    barrier_lgkm();
    if (s + 1 < 8) {
#pragma unroll
      for (int i = 0; i < 4; ++i) *(bf16x8*)&As[swz(arow, ahalf * 64 + i * 16) >> 1] = pa[i];
      store_b8(Bs[cur ^ 1], c2, kq * 16, pb);
    }
  }
  // epilogue: weighted atomic combine
#pragma unroll
  for (int i = 0; i < 4; ++i) {
#pragma unroll
    for (int r = 0; r < 4; ++r) {
      int rl = wr * 64 + i * 16 + lq * 4 + r;
      if (rl < rows) {
        int gr = row0 + rl;
        int tok = row_token[gr];
        float wgt = row_w[gr];
        float* orow = out + (size_t)tok * HD + n0 + wc * 64;
#pragma unroll
        for (int j = 0; j < 4; ++j)
          atomicAdd(&orow[j * 16 + l15], acc[i][j][r] * wgt);
      }
    }
  }
}

// ---------------- launch ----------------
extern "C" void kernel_launch(void* const* d_in, const int* in_sizes, int n_in,
                              void* d_out, int out_size, void* d_ws, size_t ws_size,
                              hipStream_t stream) {
  const float* hidden = (const float*)d_in[0];
  const float* gate_w = (const float*)d_in[1];
  const float* w13    = (const float*)d_in[2];
  const float* w2     = (const float*)d_in[3];
  const float* sw13   = (const float*)d_in[4];
  const float* sw2    = (const float*)d_in[5];
  float* out = (float*)d_out;

  char* ws = (char*)d_ws;
  size_t off = 0;
  __bf16* hbuf    = (__bf16*)(ws + off); off += (size_t)NROWS * IMID * 2;   // 37.7 MB
  __bf16* hidden_bf = (__bf16*)(ws + off); off += (size_t)T_TOK * HD * 2;   // 16.8 MB
  float* logits  = (float*)(ws + off);  off += (size_t)T_TOK * NE * 4;      //  1.0 MB
  int*   topk_id = (int*)(ws + off);    off += (size_t)NPAIR * 4;
  float* pair_w  = (float*)(ws + off);  off += (size_t)NPAIR * 4;
  int*   row_tok = (int*)(ws + off);    off += (size_t)NROWS * 4;
  float* row_w   = (float*)(ws + off);  off += (size_t)NROWS * 4;
  int*   counts  = (int*)(ws + off);    off += 512;
  int*   curs    = (int*)(ws + off);    off += 512;
  int*   offs    = (int*)(ws + off);    off += 512;
  int2*  tiles   = (int2*)(ws + off);   off += MAXT2 * 8;
  // ~56.2 MB of d_ws

  init_kernel<<<T_TOK * HD / 4 / 256, 256, 0, stream>>>((float4*)out, counts, curs);
  cvt_kernel<<<T_TOK * HD / 8 / 256, 256, 0, stream>>>((const float4*)hidden, (bf16x8*)hidden_bf);
  logits_kernel<<<T_TOK / 64, 256, 0, stream>>>(hidden, gate_w, logits);
  top8_kernel<<<T_TOK / 4, 256, 0, stream>>>(logits, topk_id, pair_w, counts);
  scan_kernel<<<1, 64, 0, stream>>>(counts, offs, tiles);
  scatter_kernel<<<NROWS / 256, 256, 0, stream>>>(topk_id, pair_w, offs, curs, row_tok, row_w);
  gemm1_kernel<<<dim3(8, MAXT2), 512, 0, stream>>>(hidden_bf, w13, sw13, row_tok, tiles, hbuf);
  gemm2_kernel<<<dim3(16, MAXT2), 512, 0, stream>>>(hbuf, w2, sw2, row_tok, row_w, tiles, out);
}

// Round 4
// 829.034 us; speedup vs baseline: 2.0708x; 2.0708x over previous
//
#include <hip/hip_runtime.h>
#include <hip/hip_bf16.h>

// ---------------- problem constants ----------------
#define T_TOK 4096
#define HD    2048
#define NE    64
#define TOPK  8
#define IMID  512
#define N13   1024                 // 2*I
#define NPAIR (T_TOK*TOPK)         // 32768
#define NROWS (NPAIR + T_TOK)      // 36864
#define MAXT2 208                  // >= 64 + 32768/256 + 16
#define RSCALE 2.5f

typedef __attribute__((ext_vector_type(8))) __bf16 bf16x8;
typedef __attribute__((ext_vector_type(4))) __bf16 bf16x4;
typedef __attribute__((ext_vector_type(4))) float  f32x4;

// ---------------- init: zero out + counters ----------------
__global__ __launch_bounds__(256) void init_kernel(float4* __restrict__ out4,
                                                   int* __restrict__ counts,
                                                   int* __restrict__ curs) {
  int gid = blockIdx.x * 256 + threadIdx.x;
  float4 z; z.x = z.y = z.z = z.w = 0.f;
  out4[gid] = z;
  if (gid < NE + 1) { counts[gid] = 0; curs[gid] = 0; }
}

// ---------------- hidden fp32 -> bf16 prepass ----------------
__global__ __launch_bounds__(256) void cvt_kernel(const float4* __restrict__ hs4,
                                                  bf16x8* __restrict__ hb8) {
  int gid = blockIdx.x * 256 + threadIdx.x;
  float4 a = hs4[2 * gid], b = hs4[2 * gid + 1];
  bf16x8 v = { (__bf16)a.x, (__bf16)a.y, (__bf16)a.z, (__bf16)a.w,
               (__bf16)b.x, (__bf16)b.y, (__bf16)b.z, (__bf16)b.w };
  hb8[gid] = v;
}

// ---------------- router logits ----------------
__global__ __launch_bounds__(256) void logits_kernel(const float* __restrict__ hs,
                                                     const float* __restrict__ gw,
                                                     float* __restrict__ logits) {
  __shared__ float hsm[64][64];
  __shared__ float gwm[64][64];
  int tid = threadIdx.x;
  int tb = blockIdx.x * 64;
  int tok = tid & 63, kq = tid >> 6;
  int tq = (tid & 15) * 4, eq = (tid >> 4) * 4;
  float acc[4][4] = {};
  for (int c = 0; c < 32; ++c) {
    int kb = c * 64;
#pragma unroll
    for (int it = 0; it < 4; ++it) {
      int k4 = kq * 16 + it * 4;
      float4 f = *(const float4*)&hs[(size_t)(tb + tok) * HD + kb + k4];
      hsm[k4 + 0][tok] = f.x; hsm[k4 + 1][tok] = f.y;
      hsm[k4 + 2][tok] = f.z; hsm[k4 + 3][tok] = f.w;
      int q = tid + it * 256;
      int grow = q >> 4, gc = (q & 15) * 4;
      *(float4*)&gwm[grow][gc] = *(const float4*)&gw[(size_t)(kb + grow) * NE + gc];
    }
    __syncthreads();
#pragma unroll 8
    for (int k = 0; k < 64; ++k) {
      float4 g = *(const float4*)&gwm[k][eq];
      float h0 = hsm[k][tq + 0], h1 = hsm[k][tq + 1];
      float h2 = hsm[k][tq + 2], h3 = hsm[k][tq + 3];
      acc[0][0] += h0 * g.x; acc[0][1] += h0 * g.y; acc[0][2] += h0 * g.z; acc[0][3] += h0 * g.w;
      acc[1][0] += h1 * g.x; acc[1][1] += h1 * g.y; acc[1][2] += h1 * g.z; acc[1][3] += h1 * g.w;
      acc[2][0] += h2 * g.x; acc[2][1] += h2 * g.y; acc[2][2] += h2 * g.z; acc[2][3] += h2 * g.w;
      acc[3][0] += h3 * g.x; acc[3][1] += h3 * g.y; acc[3][2] += h3 * g.z; acc[3][3] += h3 * g.w;
    }
    __syncthreads();
  }
#pragma unroll
  for (int i = 0; i < 4; ++i)
#pragma unroll
    for (int j = 0; j < 4; ++j)
      logits[(size_t)(tb + tq + i) * NE + eq + j] = acc[i][j];
}

// ---------------- sigmoid + top-8 ----------------
__global__ __launch_bounds__(256) void top8_kernel(const float* __restrict__ logits,
                                                   int* __restrict__ topk_id,
                                                   float* __restrict__ pair_w,
                                                   int* __restrict__ counts) {
  int lane = threadIdx.x & 63;
  int t = blockIdx.x * 4 + (threadIdx.x >> 6);
  float v = logits[(size_t)t * NE + lane];
  float s = 1.f / (1.f + __expf(-v));
  float cur = s, ssum = 0.f;
  int myid = 0; float myw = 0.f;
  for (int k = 0; k < TOPK; ++k) {
    float bv = cur; int bi = lane;
#pragma unroll
    for (int off = 32; off >= 1; off >>= 1) {
      float ov = __shfl_xor(bv, off);
      int   oi = __shfl_xor(bi, off);
      if (ov > bv || (ov == bv && oi < bi)) { bv = ov; bi = oi; }
    }
    ssum += bv;
    if (lane == k) { myid = bi; myw = bv; }
    if (lane == bi) cur = -1.f;
  }
  if (lane < TOPK) {
    topk_id[(size_t)t * TOPK + lane] = myid;
    pair_w[(size_t)t * TOPK + lane] = myw / ssum * RSCALE;
    atomicAdd(&counts[myid], 1);
  }
}

// ---------------- scan ----------------
__global__ void scan_kernel(int* __restrict__ counts, int* __restrict__ offs,
                            int2* __restrict__ tiles) {
  if (threadIdx.x != 0) return;
  counts[NE] = T_TOK;
  int off = 0, tix = 0;
  for (int e = 0; e <= NE; ++e) {
    offs[e] = off;
    int c = counts[e];
    int nt = (c + 255) >> 8;
    for (int i = 0; i < nt; ++i) {
      int rr = c - i * 256; if (rr > 256) rr = 256;
      tiles[tix++] = make_int2(off + i * 256, (e << 16) | rr);
    }
    off += c;
  }
  for (; tix < MAXT2; ++tix) tiles[tix] = make_int2(0, 0);
}

// ---------------- scatter ----------------
__global__ __launch_bounds__(256) void scatter_kernel(const int* __restrict__ topk_id,
                                                      const float* __restrict__ pair_w,
                                                      const int* __restrict__ offs,
                                                      int* __restrict__ curs,
                                                      int* __restrict__ row_token,
                                                      float* __restrict__ row_w) {
  int p = blockIdx.x * 256 + threadIdx.x;
  int dst, t; float w;
  if (p < NPAIR) {
    t = p >> 3; int e = topk_id[p]; w = pair_w[p];
    dst = offs[e] + atomicAdd(&curs[e], 1);
  } else {
    t = p - NPAIR; w = 1.0f;
    dst = offs[NE] + t;
  }
  row_token[dst] = t;
  row_w[dst] = w;
}

// ---------------- helpers ----------------
__device__ __forceinline__ int swz(int row, int kbyte) {     // [row][64 bf16 = 128B]
  return row * 128 + (kbyte ^ ((row & 7) << 4));
}
__device__ __forceinline__ void barrier_lgkm() {
  asm volatile("s_waitcnt lgkmcnt(0)" ::: "memory");
  __builtin_amdgcn_s_barrier();
  __builtin_amdgcn_sched_barrier(0);
}
__device__ __forceinline__ void barrier_plain() {
  __builtin_amdgcn_sched_barrier(0);
  __builtin_amdgcn_s_barrier();
  __builtin_amdgcn_sched_barrier(0);
}
__device__ __forceinline__ void wait_vm0() {
  asm volatile("s_waitcnt vmcnt(0)" ::: "memory");
}
__device__ __forceinline__ void glds16(const void* g, void* l) {
  __builtin_amdgcn_global_load_lds((const __attribute__((address_space(1))) void*)g,
                                   (__attribute__((address_space(3))) void*)l, 16, 0, 0);
}
// transpose 4 k-rows x 2 cols fp32 -> two bf16x4 column slivers (swizzled write)
__device__ __forceinline__ void store_b4(__bf16* Bs, int c2, int kbyte, const float2* p) {
  bf16x4 c0 = { (__bf16)p[0].x, (__bf16)p[1].x, (__bf16)p[2].x, (__bf16)p[3].x };
  bf16x4 c1 = { (__bf16)p[0].y, (__bf16)p[1].y, (__bf16)p[2].y, (__bf16)p[3].y };
  *(bf16x4*)&Bs[swz(c2,     kbyte) >> 1] = c0;
  *(bf16x4*)&Bs[swz(c2 + 1, kbyte) >> 1] = c1;
}
// transpose 8 k-rows x 2 cols fp32 -> two bf16x8 column slivers (swizzled write)
__device__ __forceinline__ void store_b8(__bf16* Bs, int c2, int kbyte, const float2* p) {
  bf16x8 c0 = { (__bf16)p[0].x, (__bf16)p[1].x, (__bf16)p[2].x, (__bf16)p[3].x,
                (__bf16)p[4].x, (__bf16)p[5].x, (__bf16)p[6].x, (__bf16)p[7].x };
  bf16x8 c1 = { (__bf16)p[0].y, (__bf16)p[1].y, (__bf16)p[2].y, (__bf16)p[3].y,
                (__bf16)p[4].y, (__bf16)p[5].y, (__bf16)p[6].y, (__bf16)p[7].y };
  *(bf16x8*)&Bs[swz(c2,     kbyte) >> 1] = c0;
  *(bf16x8*)&Bs[swz(c2 + 1, kbyte) >> 1] = c1;
}

// ---------------- grouped GEMM1: BM=256, 64 g-cols + 64 u-cols, BK=64 ------------------
// A: bf16 gather via global_load_lds, pre-swizzled source, single-buffer 32KB.
// B: fp32 reg-prefetch + cvt/transpose, double-buffer 2x16KB x2. LDS=64KB, 2 blocks/CU.
__global__ __launch_bounds__(512, 4) void gemm1_kernel(const __bf16* __restrict__ hidden_bf,
                                                       const float* __restrict__ w13,
                                                       const float* __restrict__ sw13,
                                                       const int* __restrict__ row_token,
                                                       const int2* __restrict__ tiles,
                                                       __bf16* __restrict__ hbuf) {
  int2 td = tiles[blockIdx.y];
  int rows = td.y & 0xFFFF;
  if (rows == 0) return;
  int e = td.y >> 16, row0 = td.x;
  const float* W = (e < NE) ? (w13 + (size_t)e * (HD * N13)) : sw13;  // [2048][1024]
  int n0 = blockIdx.x * 64;                                           // gate cols; up at +512

  __shared__ __bf16 As[256 * 64];      // 32 KB, single
  __shared__ __bf16 Bgs[2][64 * 64];   // 16 KB
  __shared__ __bf16 Bus[2][64 * 64];   // 16 KB

  int tid = threadIdx.x;
  int lane = tid & 63, wv = tid >> 6;
  int l15 = lane & 15, lq = lane >> 4;

  // A glds: wave wv stages rows [wv*32, wv*32+32), 4 instrs x (8 rows x 128B)
  // lane l: row = wv*32 + i*8 + (l>>3); source k-chunk pre-swizzled so linear LDS == swz layout
  int kswz = (((lane & 7) ^ (lane >> 3)) << 3);      // element offset of 8-elem chunk
  const __bf16* Abase[4];
#pragma unroll
  for (int i = 0; i < 4; ++i) {
    int grow = row0 + wv * 32 + i * 8 + (lane >> 3);
    if (grow >= NROWS) grow = NROWS - 1;
    Abase[i] = hidden_bf + (size_t)row_token[grow] * HD + kswz;
  }
  // B: col-pair c2 + 4 k-rows per thread per matrix
  int c2 = (tid & 31) * 2, kq = tid >> 5;            // kq in [0,16)
  const float* Bg0 = W + (size_t)(kq * 4) * N13 + n0 + c2;
  const float* Bu0 = Bg0 + 512;

  // ---- prologue: stage step 0 ----
  float2 pg[4], pu[4];
#pragma unroll
  for (int r = 0; r < 4; ++r) {
    pg[r] = *(const float2*)(Bg0 + (size_t)r * N13);
    pu[r] = *(const float2*)(Bu0 + (size_t)r * N13);
  }
#pragma unroll
  for (int i = 0; i < 4; ++i)
    glds16(Abase[i], &As[wv * 2048 + i * 512]);
  store_b4(Bgs[0], c2, kq * 8, pg);
  store_b4(Bus[0], c2, kq * 8, pu);
  wait_vm0();
  barrier_lgkm();

  f32x4 accg[2][4], accu[2][4];
#pragma unroll
  for (int i = 0; i < 2; ++i)
#pragma unroll
    for (int j = 0; j < 4; ++j) { accg[i][j] = (f32x4)(0.f); accu[i][j] = (f32x4)(0.f); }

  for (int s = 0; s < 32; ++s) {
    int cur = s & 1;
    if (s + 1 < 32) {                  // issue next B loads (in flight during MFMA)
      const float* Bg2 = Bg0 + (size_t)(s + 1) * 64 * N13;
      const float* Bu2 = Bu0 + (size_t)(s + 1) * 64 * N13;
#pragma unroll
      for (int r = 0; r < 4; ++r) {
        pg[r] = *(const float2*)(Bg2 + (size_t)r * N13);
        pu[r] = *(const float2*)(Bu2 + (size_t)r * N13);
      }
    }
#pragma unroll
    for (int kk = 0; kk < 2; ++kk) {
      int koff = kk * 64 + lq * 16;
      bf16x8 a0 = *(const bf16x8*)&As[swz(wv * 32 + l15,      koff) >> 1];
      bf16x8 a1 = *(const bf16x8*)&As[swz(wv * 32 + 16 + l15, koff) >> 1];
      {
        bf16x8 b[4];
#pragma unroll
        for (int j = 0; j < 4; ++j) b[j] = *(const bf16x8*)&Bgs[cur][swz(j * 16 + l15, koff) >> 1];
#pragma unroll
        for (int j = 0; j < 4; ++j) {
          accg[0][j] = __builtin_amdgcn_mfma_f32_16x16x32_bf16(a0, b[j], accg[0][j], 0, 0, 0);
          accg[1][j] = __builtin_amdgcn_mfma_f32_16x16x32_bf16(a1, b[j], accg[1][j], 0, 0, 0);
        }
      }
      {
        bf16x8 b[4];
#pragma unroll
        for (int j = 0; j < 4; ++j) b[j] = *(const bf16x8*)&Bus[cur][swz(j * 16 + l15, koff) >> 1];
#pragma unroll
        for (int j = 0; j < 4; ++j) {
          accu[0][j] = __builtin_amdgcn_mfma_f32_16x16x32_bf16(a0, b[j], accu[0][j], 0, 0, 0);
          accu[1][j] = __builtin_amdgcn_mfma_f32_16x16x32_bf16(a1, b[j], accu[1][j], 0, 0, 0);
        }
      }
    }
    barrier_plain();                   // all As/B[cur] reads done
    if (s + 1 < 32) {
#pragma unroll
      for (int i = 0; i < 4; ++i)      // overwrite As for step s+1
        glds16(Abase[i] + (s + 1) * 64, &As[wv * 2048 + i * 512]);
      store_b4(Bgs[cur ^ 1], c2, kq * 8, pg);   // waits B vmcnt on reg use
      store_b4(Bus[cur ^ 1], c2, kq * 8, pu);
      wait_vm0();                      // A glds complete
    }
    barrier_lgkm();
  }
  // epilogue: h = silu(g)*u  (wave rows [wv*32, +32))
#pragma unroll
  for (int mi = 0; mi < 2; ++mi) {
#pragma unroll
    for (int r = 0; r < 4; ++r) {
      int rl = wv * 32 + mi * 16 + lq * 4 + r;
      if (rl < rows) {
        size_t hrow = (size_t)(row0 + rl) * IMID;
#pragma unroll
        for (int j = 0; j < 4; ++j) {
          float g = accg[mi][j][r], u = accu[mi][j][r];
          float hv = g * u / (1.f + __expf(-g));
          hbuf[hrow + n0 + j * 16 + l15] = (__bf16)hv;
        }
      }
    }
  }
}

// ---------------- grouped GEMM2: BM=256, BN=128, BK=64, atomic combine ------------------
__global__ __launch_bounds__(512, 4) void gemm2_kernel(const __bf16* __restrict__ hbuf,
                                                       const float* __restrict__ w2,
                                                       const float* __restrict__ sw2,
                                                       const int* __restrict__ row_token,
                                                       const float* __restrict__ row_w,
                                                       const int2* __restrict__ tiles,
                                                       float* __restrict__ out) {
  int2 td = tiles[blockIdx.y];
  int rows = td.y & 0xFFFF;
  if (rows == 0) return;
  int e = td.y >> 16, row0 = td.x;
  const float* W = (e < NE) ? (w2 + (size_t)e * (IMID * HD)) : sw2;   // [512][2048]
  int n0 = blockIdx.x * 128;

  __shared__ __bf16 As[256 * 64];      // 32 KB single
  __shared__ __bf16 Bs[2][128 * 64];   // 32 KB dbuf

  int tid = threadIdx.x;
  int lane = tid & 63, wv = tid >> 6, wr = wv >> 1, wc = wv & 1;
  int l15 = lane & 15, lq = lane >> 4;

  int kswz = (((lane & 7) ^ (lane >> 3)) << 3);
  const __bf16* Abase[4];
#pragma unroll
  for (int i = 0; i < 4; ++i) {
    int grow = row0 + wv * 32 + i * 8 + (lane >> 3);
    if (grow >= NROWS) grow = NROWS - 1;
    Abase[i] = hbuf + (size_t)grow * IMID + kswz;
  }

  int c2 = (tid & 63) * 2, kq = tid >> 6;            // kq in [0,8): 8 k-rows each
  const float* Bp0 = W + (size_t)(kq * 8) * HD + n0 + c2;

  float2 pb[8];
#pragma unroll
  for (int r = 0; r < 8; ++r) pb[r] = *(const float2*)(Bp0 + (size_t)r * HD);
#pragma unroll
  for (int i = 0; i < 4; ++i)
    glds16(Abase[i], &As[wv * 2048 + i * 512]);
  store_b8(Bs[0], c2, kq * 16, pb);
  wait_vm0();
  barrier_lgkm();

  f32x4 acc[4][4];
#pragma unroll
  for (int i = 0; i < 4; ++i)
#pragma unroll
    for (int j = 0; j < 4; ++j) acc[i][j] = (f32x4)(0.f);

  for (int s = 0; s < 8; ++s) {
    int cur = s & 1;
    if (s + 1 < 8) {
      const float* Bp2 = Bp0 + (size_t)(s + 1) * 64 * HD;
#pragma unroll
      for (int r = 0; r < 8; ++r) pb[r] = *(const float2*)(Bp2 + (size_t)r * HD);
    }
#pragma unroll
    for (int kk = 0; kk < 2; ++kk) {
      int koff = kk * 64 + lq * 16;
      bf16x8 a[4];
#pragma unroll
      for (int i = 0; i < 4; ++i)
        a[i] = *(const bf16x8*)&As[swz(wr * 64 + i * 16 + l15, koff) >> 1];
#pragma unroll
      for (int j = 0; j < 4; ++j) {
        bf16x8 b = *(const bf16x8*)&Bs[cur][swz(wc * 64 + j * 16 + l15, koff) >> 1];
#pragma unroll
        for (int i = 0; i < 4; ++i)
          acc[i][j] = __builtin_amdgcn_mfma_f32_16x16x32_bf16(a[i], b, acc[i][j], 0, 0, 0);
      }
    }
    barrier_plain();
    if (s + 1 < 8) {
#pragma unroll
      for (int i = 0; i < 4; ++i)
        glds16(Abase[i] + (s + 1) * 64, &As[wv * 2048 + i * 512]);
      store_b8(Bs[cur ^ 1], c2, kq * 16, pb);
      wait_vm0();
    }
    barrier_lgkm();
  }
  // epilogue: weighted atomic combine
#pragma unroll
  for (int i = 0; i < 4; ++i) {
#pragma unroll
    for (int r = 0; r < 4; ++r) {
      int rl = wr * 64 + i * 16 + lq * 4 + r;
      if (rl < rows) {
        int gr = row0 + rl;
        int tok = row_token[gr];
        float wgt = row_w[gr];
        float* orow = out + (size_t)tok * HD + n0 + wc * 64;
#pragma unroll
        for (int j = 0; j < 4; ++j)
          atomicAdd(&orow[j * 16 + l15], acc[i][j][r] * wgt);
      }
    }
  }
}

// ---------------- launch ----------------
extern "C" void kernel_launch(void* const* d_in, const int* in_sizes, int n_in,
                              void* d_out, int out_size, void* d_ws, size_t ws_size,
                              hipStream_t stream) {
  const float* hidden = (const float*)d_in[0];
  const float* gate_w = (const float*)d_in[1];
  const float* w13    = (const float*)d_in[2];
  const float* w2     = (const float*)d_in[3];
  const float* sw13   = (const float*)d_in[4];
  const float* sw2    = (const float*)d_in[5];
  float* out = (float*)d_out;

  char* ws = (char*)d_ws;
  size_t off = 0;
  __bf16* hbuf      = (__bf16*)(ws + off); off += (size_t)NROWS * IMID * 2;
  __bf16* hidden_bf = (__bf16*)(ws + off); off += (size_t)T_TOK * HD * 2;
  float* logits  = (float*)(ws + off);  off += (size_t)T_TOK * NE * 4;
  int*   topk_id = (int*)(ws + off);    off += (size_t)NPAIR * 4;
  float* pair_w  = (float*)(ws + off);  off += (size_t)NPAIR * 4;
  int*   row_tok = (int*)(ws + off);    off += (size_t)NROWS * 4;
  float* row_w   = (float*)(ws + off);  off += (size_t)NROWS * 4;
  int*   counts  = (int*)(ws + off);    off += 512;
  int*   curs    = (int*)(ws + off);    off += 512;
  int*   offs    = (int*)(ws + off);    off += 512;
  int2*  tiles   = (int2*)(ws + off);   off += MAXT2 * 8;

  init_kernel<<<T_TOK * HD / 4 / 256, 256, 0, stream>>>((float4*)out, counts, curs);
  cvt_kernel<<<T_TOK * HD / 8 / 256, 256, 0, stream>>>((const float4*)hidden, (bf16x8*)hidden_bf);
  logits_kernel<<<T_TOK / 64, 256, 0, stream>>>(hidden, gate_w, logits);
  top8_kernel<<<T_TOK / 4, 256, 0, stream>>>(logits, topk_id, pair_w, counts);
  scan_kernel<<<1, 64, 0, stream>>>(counts, offs, tiles);
  scatter_kernel<<<NROWS / 256, 256, 0, stream>>>(topk_id, pair_w, offs, curs, row_tok, row_w);
  gemm1_kernel<<<dim3(8, MAXT2), 512, 0, stream>>>(hidden_bf, w13, sw13, row_tok, tiles, hbuf);
  gemm2_kernel<<<dim3(16, MAXT2), 512, 0, stream>>>(hbuf, w2, sw2, row_tok, row_w, tiles, out);
}